// Round 6
// baseline (972.257 us; speedup 1.0000x reference)
//
#include <hip/hip_runtime.h>

typedef unsigned short u16;
typedef unsigned int u32;
typedef __bf16 bf16x8 __attribute__((ext_vector_type(8)));
typedef float fx4 __attribute__((ext_vector_type(4)));

__device__ __forceinline__ float bf2f(u16 u) {
    return __uint_as_float(((u32)u) << 16);
}
__device__ __forceinline__ u16 f2bf(float f) {
    u32 x = __float_as_uint(f);
    u32 r = (x + 0x7fffu + ((x >> 16) & 1u)) >> 16;
    return (u16)r;
}
__device__ __forceinline__ ushort4 f4_to_bf4(float4 v) {
    ushort4 r;
    r.x = f2bf(v.x);
    r.y = f2bf(v.y);
    r.z = f2bf(v.z);
    r.w = f2bf(v.w);
    return r;
}

#define MFMA16(a, b, c) __builtin_amdgcn_mfma_f32_16x16x32_bf16((a), (b), (c), 0, 0, 0)

// ---------------------------------------------------------------------------
// GEMM: C[M][N] = A[M][K] * B[N][K]^T + bias[N]
// B, bias fp32 (harness inputs). A fp32 (A_F32=1) or bf16 ws (A_F32=0).
// MODE 0: write fp32 C[M][N] to out (d_out is float per reference output).
// MODE 1: qkv scatter (bf16) to q/k/v [bh][s][d] in ws.
// ---------------------------------------------------------------------------
template <int MODE, int A_F32>
__global__ __launch_bounds__(256, 2) void gemm_bt(const void* __restrict__ Av,
                                                  const float* __restrict__ Bw,
                                                  const float* __restrict__ bias,
                                                  void* __restrict__ outv,
                                                  int M, int N, int K) {
    __shared__ __align__(16) u16 As[128 * 40];  // 128 x 32 bf16 tile, stride 40
    __shared__ __align__(16) u16 Bs[128 * 40];

    const int tid = threadIdx.x;
    const int lane = tid & 63;
    const int wave = tid >> 6;
    const int quad = lane >> 4;
    const int m16 = lane & 15;
    const int wm = wave >> 1, wn = wave & 1;
    const int bm = blockIdx.y * 128, bn = blockIdx.x * 128;

    const fx4 zero4 = {0.f, 0.f, 0.f, 0.f};
    fx4 acc[4][4];
#pragma unroll
    for (int i = 0; i < 4; ++i)
#pragma unroll
        for (int j = 0; j < 4; ++j) acc[i][j] = zero4;

    const int nk = K >> 5;
    for (int kt = 0; kt < nk; ++kt) {
        const int k0 = kt << 5;
        if (A_F32) {
            const float* Af = (const float*)Av;
#pragma unroll
            for (int i = 0; i < 4; ++i) {
                int c = i * 256 + tid;
                int row = c >> 3, col = (c & 7) << 2;
                float4 a4 =
                    *(const float4*)&Af[(size_t)(bm + row) * K + k0 + col];
                *(ushort4*)&As[row * 40 + col] = f4_to_bf4(a4);
            }
        } else {
            const u16* Ab = (const u16*)Av;
#pragma unroll
            for (int i = 0; i < 2; ++i) {
                int c = i * 256 + tid;
                int row = c >> 2, col = (c & 3) << 3;
                *(uint4*)&As[row * 40 + col] =
                    *(const uint4*)&Ab[(size_t)(bm + row) * K + k0 + col];
            }
        }
#pragma unroll
        for (int i = 0; i < 4; ++i) {
            int c = i * 256 + tid;
            int row = c >> 3, col = (c & 7) << 2;
            float4 b4 = *(const float4*)&Bw[(size_t)(bn + row) * K + k0 + col];
            *(ushort4*)&Bs[row * 40 + col] = f4_to_bf4(b4);
        }
        __syncthreads();
        bf16x8 af[4], bfr[4];
#pragma unroll
        for (int t = 0; t < 4; ++t) {
            af[t] = *(const bf16x8*)&As[(wm * 64 + t * 16 + m16) * 40 + quad * 8];
            bfr[t] = *(const bf16x8*)&Bs[(wn * 64 + t * 16 + m16) * 40 + quad * 8];
        }
#pragma unroll
        for (int mt = 0; mt < 4; ++mt)
#pragma unroll
            for (int nt = 0; nt < 4; ++nt)
                acc[mt][nt] = MFMA16(af[mt], bfr[nt], acc[mt][nt]);
        __syncthreads();
    }

    u16* qb = (u16*)outv;
    u16* kb_ = qb + 8388608;
    u16* vb = qb + 16777216;
    float* outf = (float*)outv;
#pragma unroll
    for (int mt = 0; mt < 4; ++mt) {
#pragma unroll
        for (int r = 0; r < 4; ++r) {
            int row = bm + wm * 64 + mt * 16 + quad * 4 + r;
#pragma unroll
            for (int nt = 0; nt < 4; ++nt) {
                int col = bn + wn * 64 + nt * 16 + m16;
                float v = acc[mt][nt][r] + bias[col];
                if (MODE == 0) {
                    outf[(size_t)row * N + col] = v;  // fp32 output
                } else {
                    int which = col >> 11;
                    int h = (col >> 7) & 15;
                    int d = col & 127;
                    int b = row >> 11;
                    int s = row & 2047;
                    u16* dst = (which == 0) ? qb : ((which == 1) ? kb_ : vb);
                    dst[(size_t)((b * 16 + h) * 2048 + s) * 128 + d] = f2bf(v);
                }
            }
        }
    }
}

// ---------------------------------------------------------------------------
// RoPE in place on q and k (bf16 ws), layout [bh][s][128]; pair (i, i+64).
// ---------------------------------------------------------------------------
__global__ __launch_bounds__(256) void rope_kernel(u16* __restrict__ q,
                                                   u16* __restrict__ k) {
    int t = blockIdx.x * 256 + threadIdx.x;
    int i = t & 63;
    int s = (t >> 6) & 2047;
    int bh = t >> 17;
    float inv = exp2f(-(float)i * 0.2076205059304595f);  // 10000^(-i/64)
    float ang = (float)s * inv;
    float sn, cs;
    sincosf(ang, &sn, &cs);
    size_t base = ((size_t)bh * 2048 + s) * 128 + i;
    {
        float x1 = bf2f(q[base]), x2 = bf2f(q[base + 64]);
        q[base] = f2bf(x1 * cs - x2 * sn);
        q[base + 64] = f2bf(x1 * sn + x2 * cs);
    }
    {
        float x1 = bf2f(k[base]), x2 = bf2f(k[base + 64]);
        k[base] = f2bf(x1 * cs - x2 * sn);
        k[base + 64] = f2bf(x1 * sn + x2 * cs);
    }
}

// ---------------------------------------------------------------------------
// V transpose: [bh][s][d] -> [bh][d][s] (bf16 ws).
// ---------------------------------------------------------------------------
__global__ __launch_bounds__(256) void vtrans_kernel(const u16* __restrict__ v,
                                                     u16* __restrict__ vt) {
    __shared__ __align__(16) u16 L[128 * 66];
    const int tid = threadIdx.x;
    const int kb = blockIdx.x * 64;
    const int bh = blockIdx.y;
    const u16* vp = v + (size_t)bh * 2048 * 128;
    u16* op = vt + (size_t)bh * 128 * 2048;
#pragma unroll
    for (int i = 0; i < 4; ++i) {
        int c = i * 256 + tid;
        int t = c >> 4, d8 = (c & 15) << 3;
        uint4 x = *(const uint4*)&vp[(kb + t) * 128 + d8];
        const u16* xs = (const u16*)&x;
#pragma unroll
        for (int j = 0; j < 8; ++j) L[(d8 + j) * 66 + t] = xs[j];
    }
    __syncthreads();
#pragma unroll
    for (int i = 0; i < 4; ++i) {
        int c = i * 256 + tid;
        int d = c >> 3, t8 = (c & 7) << 3;
        uint4 x;
        u16* xs = (u16*)&x;
#pragma unroll
        for (int j = 0; j < 8; ++j) xs[j] = L[d * 66 + t8 + j];
        *(uint4*)&op[(size_t)d * 2048 + kb + t8] = x;
    }
}

// ---------------------------------------------------------------------------
// Flash attention (causal). Grid (S/64, B*H). 256 threads = 4 waves;
// wave w owns q-rows w*16..w*16+15. Transparent LDS softmax.
// ---------------------------------------------------------------------------
__global__ __launch_bounds__(256, 2) void attn_kernel(const u16* __restrict__ q,
                                                      const u16* __restrict__ k,
                                                      const u16* __restrict__ vt,
                                                      u16* __restrict__ ctx) {
    __shared__ __align__(16) u16 Ks[64 * 136];    // K [token][d]
    __shared__ __align__(16) u16 Vs[128 * 72];    // V^T [d][token]
    __shared__ float Sf[64 * 68];                 // fp32 scores [row][col]
    __shared__ __align__(16) u16 Pb[64 * 72];     // bf16 P [row][col]
    __shared__ float mrow[64], lrow[64], arow[64];

    const int tid = threadIdx.x;
    const int lane = tid & 63;
    const int wave = tid >> 6;
    const int quad = lane >> 4;
    const int m16 = lane & 15;
    const int qt = blockIdx.x;
    const int bh = blockIdx.y;
    const int b = bh >> 4, h = bh & 15;
    const int qbase = qt * 64;
    const int wrow = qbase + wave * 16;
    const u16* qp = q + (size_t)bh * 2048 * 128;
    const u16* kp = k + (size_t)bh * 2048 * 128;
    const u16* vp = vt + (size_t)bh * 128 * 2048;
    const float scale = 0.08838834764831845f;  // 1/sqrt(128)

    if (tid < 64) {
        mrow[tid] = -1e30f;
        lrow[tid] = 0.f;
    }

    bf16x8 qf[4];
#pragma unroll
    for (int c = 0; c < 4; ++c)
        qf[c] = *(const bf16x8*)&qp[(wrow + m16) * 128 + c * 32 + quad * 8];

    const fx4 zero4 = {0.f, 0.f, 0.f, 0.f};
    fx4 o[8];
#pragma unroll
    for (int i = 0; i < 8; ++i) o[i] = zero4;

    const int nkt = qt + 1;
    for (int kt = 0; kt < nkt; ++kt) {
        const int kb = kt * 64;
#pragma unroll
        for (int i = 0; i < 4; ++i) {
            int c = i * 256 + tid;
            {
                int t = c >> 4, d8 = (c & 15) << 3;
                *(uint4*)&Ks[t * 136 + d8] =
                    *(const uint4*)&kp[(kb + t) * 128 + d8];
            }
            {
                int d = c >> 3, t8 = (c & 7) << 3;
                *(uint4*)&Vs[d * 72 + t8] =
                    *(const uint4*)&vp[d * 2048 + kb + t8];
            }
        }
        __syncthreads();

        fx4 sc[4];
#pragma unroll
        for (int nt = 0; nt < 4; ++nt) sc[nt] = zero4;
#pragma unroll
        for (int c = 0; c < 4; ++c)
#pragma unroll
            for (int nt = 0; nt < 4; ++nt) {
                bf16x8 kf =
                    *(const bf16x8*)&Ks[(nt * 16 + m16) * 136 + c * 32 + quad * 8];
                sc[nt] = MFMA16(qf[c], kf, sc[nt]);
            }
#pragma unroll
        for (int nt = 0; nt < 4; ++nt)
#pragma unroll
            for (int r = 0; r < 4; ++r)
                Sf[(wave * 16 + quad * 4 + r) * 68 + nt * 16 + m16] =
                    sc[nt][r] * scale;
        __syncthreads();

        if (m16 == lane) {  // lane < 16: one thread per q-row
            int row = wave * 16 + lane;
            int rg = qbase + row;
            float m_old = mrow[row];
            float mx = m_old;
            for (int j = 0; j < 64; ++j) {
                float s = Sf[row * 68 + j];
                if (kb + j <= rg) mx = fmaxf(mx, s);
            }
            float alpha = __expf(m_old - mx);
            float sum = 0.f;
            for (int j = 0; j < 64; ++j) {
                float p = (kb + j <= rg) ? __expf(Sf[row * 68 + j] - mx) : 0.f;
                Pb[row * 72 + j] = f2bf(p);
                sum += p;
            }
            mrow[row] = mx;
            lrow[row] = lrow[row] * alpha + sum;
            arow[row] = alpha;
        }
        __syncthreads();

#pragma unroll
        for (int r = 0; r < 4; ++r) {
            float a = arow[wave * 16 + quad * 4 + r];
#pragma unroll
            for (int dn = 0; dn < 8; ++dn) o[dn][r] *= a;
        }
#pragma unroll
        for (int c2 = 0; c2 < 2; ++c2) {
            bf16x8 pf =
                *(const bf16x8*)&Pb[(wave * 16 + m16) * 72 + c2 * 32 + quad * 8];
#pragma unroll
            for (int dn = 0; dn < 8; ++dn) {
                bf16x8 vf =
                    *(const bf16x8*)&Vs[(dn * 16 + m16) * 72 + c2 * 32 + quad * 8];
                o[dn] = MFMA16(pf, vf, o[dn]);
            }
        }
        __syncthreads();
    }

#pragma unroll
    for (int r = 0; r < 4; ++r) {
        int row = wave * 16 + quad * 4 + r;
        int rg = qbase + row;
        float inv = 1.0f / lrow[row];
#pragma unroll
        for (int dn = 0; dn < 8; ++dn) {
            int d = dn * 16 + m16;
            ctx[((size_t)(b * 2048 + rg)) * 2048 + h * 128 + d] =
                f2bf(o[dn][r] * inv);
        }
    }
}

// ---------------------------------------------------------------------------
extern "C" void kernel_launch(void* const* d_in, const int* in_sizes, int n_in,
                              void* d_out, int out_size, void* d_ws,
                              size_t ws_size, hipStream_t stream) {
    // Inputs fp32 per setup_inputs(); OUTPUT fp32 per reference dtype
    // (R4/R5 identical-absmax evidence: bf16 writes read back as fp32).
    const float* x = (const float*)d_in[0];
    const float* wqkv_w = (const float*)d_in[1];
    const float* wqkv_b = (const float*)d_in[2];
    const float* out_w = (const float*)d_in[3];
    const float* out_b = (const float*)d_in[4];
    u16* ws = (u16*)d_ws;

    // ws: q | k | v | vt (bf16), 4 x 8388608 elements = 64 MiB. ctx reuses v.
    u16* qb = ws;
    u16* kb = ws + 8388608;
    u16* vb = ws + 16777216;
    u16* vtb = ws + 25165824;
    u16* ctx = vb;

    gemm_bt<1, 1><<<dim3(48, 32), 256, 0, stream>>>(x, wqkv_w, wqkv_b, qb,
                                                    4096, 6144, 2048);
    rope_kernel<<<16384, 256, 0, stream>>>(qb, kb);
    vtrans_kernel<<<dim3(32, 32), 256, 0, stream>>>(vb, vtb);
    attn_kernel<<<dim3(32, 32), 256, 0, stream>>>(qb, kb, vtb, ctx);
    gemm_bt<0, 0><<<dim3(16, 32), 256, 0, stream>>>(ctx, out_w, out_b, d_out,
                                                    4096, 2048, 2048);
}

// Round 7
// 629.627 us; speedup vs baseline: 1.5442x; 1.5442x over previous
//
#include <hip/hip_runtime.h>

typedef unsigned short u16;
typedef unsigned int u32;
typedef __bf16 bf16x8 __attribute__((ext_vector_type(8)));
typedef float fx4 __attribute__((ext_vector_type(4)));

__device__ __forceinline__ float bf2f(u16 u) {
    return __uint_as_float(((u32)u) << 16);
}
__device__ __forceinline__ u16 f2bf(float f) {
    u32 x = __float_as_uint(f);
    u32 r = (x + 0x7fffu + ((x >> 16) & 1u)) >> 16;
    return (u16)r;
}
__device__ __forceinline__ ushort4 f4_to_bf4(float4 v) {
    ushort4 r;
    r.x = f2bf(v.x);
    r.y = f2bf(v.y);
    r.z = f2bf(v.z);
    r.w = f2bf(v.w);
    return r;
}

#define MFMA16(a, b, c) __builtin_amdgcn_mfma_f32_16x16x32_bf16((a), (b), (c), 0, 0, 0)

// ---------------------------------------------------------------------------
// GEMM: C[M][N] = A[M][K] * B[N][K]^T + bias[N]
// B, bias fp32 (harness inputs). A fp32 (A_F32=1) or bf16 ws (A_F32=0).
// MODE 0: write fp32 C[M][N]. MODE 1: qkv scatter (bf16) to ws.
// ---------------------------------------------------------------------------
template <int MODE, int A_F32>
__global__ __launch_bounds__(256, 2) void gemm_bt(const void* __restrict__ Av,
                                                  const float* __restrict__ Bw,
                                                  const float* __restrict__ bias,
                                                  void* __restrict__ outv,
                                                  int M, int N, int K) {
    __shared__ __align__(16) u16 As[128 * 40];
    __shared__ __align__(16) u16 Bs[128 * 40];

    const int tid = threadIdx.x;
    const int lane = tid & 63;
    const int wave = tid >> 6;
    const int quad = lane >> 4;
    const int m16 = lane & 15;
    const int wm = wave >> 1, wn = wave & 1;
    const int bm = blockIdx.y * 128, bn = blockIdx.x * 128;

    const fx4 zero4 = {0.f, 0.f, 0.f, 0.f};
    fx4 acc[4][4];
#pragma unroll
    for (int i = 0; i < 4; ++i)
#pragma unroll
        for (int j = 0; j < 4; ++j) acc[i][j] = zero4;

    const int nk = K >> 5;
    for (int kt = 0; kt < nk; ++kt) {
        const int k0 = kt << 5;
        if (A_F32) {
            const float* Af = (const float*)Av;
#pragma unroll
            for (int i = 0; i < 4; ++i) {
                int c = i * 256 + tid;
                int row = c >> 3, col = (c & 7) << 2;
                float4 a4 =
                    *(const float4*)&Af[(size_t)(bm + row) * K + k0 + col];
                *(ushort4*)&As[row * 40 + col] = f4_to_bf4(a4);
            }
        } else {
            const u16* Ab = (const u16*)Av;
#pragma unroll
            for (int i = 0; i < 2; ++i) {
                int c = i * 256 + tid;
                int row = c >> 2, col = (c & 3) << 3;
                *(uint4*)&As[row * 40 + col] =
                    *(const uint4*)&Ab[(size_t)(bm + row) * K + k0 + col];
            }
        }
#pragma unroll
        for (int i = 0; i < 4; ++i) {
            int c = i * 256 + tid;
            int row = c >> 3, col = (c & 7) << 2;
            float4 b4 = *(const float4*)&Bw[(size_t)(bn + row) * K + k0 + col];
            *(ushort4*)&Bs[row * 40 + col] = f4_to_bf4(b4);
        }
        __syncthreads();
        bf16x8 af[4], bfr[4];
#pragma unroll
        for (int t = 0; t < 4; ++t) {
            af[t] = *(const bf16x8*)&As[(wm * 64 + t * 16 + m16) * 40 + quad * 8];
            bfr[t] = *(const bf16x8*)&Bs[(wn * 64 + t * 16 + m16) * 40 + quad * 8];
        }
#pragma unroll
        for (int mt = 0; mt < 4; ++mt)
#pragma unroll
            for (int nt = 0; nt < 4; ++nt)
                acc[mt][nt] = MFMA16(af[mt], bfr[nt], acc[mt][nt]);
        __syncthreads();
    }

    u16* qb = (u16*)outv;
    u16* kb_ = qb + 8388608;
    u16* vb = qb + 16777216;
    float* outf = (float*)outv;
#pragma unroll
    for (int mt = 0; mt < 4; ++mt) {
#pragma unroll
        for (int r = 0; r < 4; ++r) {
            int row = bm + wm * 64 + mt * 16 + quad * 4 + r;
#pragma unroll
            for (int nt = 0; nt < 4; ++nt) {
                int col = bn + wn * 64 + nt * 16 + m16;
                float v = acc[mt][nt][r] + bias[col];
                if (MODE == 0) {
                    outf[(size_t)row * N + col] = v;
                } else {
                    int which = col >> 11;
                    int h = (col >> 7) & 15;
                    int d = col & 127;
                    int b = row >> 11;
                    int s = row & 2047;
                    u16* dst = (which == 0) ? qb : ((which == 1) ? kb_ : vb);
                    dst[(size_t)((b * 16 + h) * 2048 + s) * 128 + d] = f2bf(v);
                }
            }
        }
    }
}

// ---------------------------------------------------------------------------
// RoPE in place on q and k (bf16 ws), layout [bh][s][128]; pair (i, i+64).
// ---------------------------------------------------------------------------
__global__ __launch_bounds__(256) void rope_kernel(u16* __restrict__ q,
                                                   u16* __restrict__ k) {
    int t = blockIdx.x * 256 + threadIdx.x;
    int i = t & 63;
    int s = (t >> 6) & 2047;
    int bh = t >> 17;
    float inv = exp2f(-(float)i * 0.2076205059304595f);  // 10000^(-i/64)
    float ang = (float)s * inv;
    float sn, cs;
    sincosf(ang, &sn, &cs);
    size_t base = ((size_t)bh * 2048 + s) * 128 + i;
    {
        float x1 = bf2f(q[base]), x2 = bf2f(q[base + 64]);
        q[base] = f2bf(x1 * cs - x2 * sn);
        q[base + 64] = f2bf(x1 * sn + x2 * cs);
    }
    {
        float x1 = bf2f(k[base]), x2 = bf2f(k[base + 64]);
        k[base] = f2bf(x1 * cs - x2 * sn);
        k[base + 64] = f2bf(x1 * sn + x2 * cs);
    }
}

// ---------------------------------------------------------------------------
// V transpose: [bh][s][d] -> [bh][d][s] (bf16 ws).
// ---------------------------------------------------------------------------
__global__ __launch_bounds__(256) void vtrans_kernel(const u16* __restrict__ v,
                                                     u16* __restrict__ vt) {
    __shared__ __align__(16) u16 L[128 * 66];
    const int tid = threadIdx.x;
    const int kb = blockIdx.x * 64;
    const int bh = blockIdx.y;
    const u16* vp = v + (size_t)bh * 2048 * 128;
    u16* op = vt + (size_t)bh * 128 * 2048;
#pragma unroll
    for (int i = 0; i < 4; ++i) {
        int c = i * 256 + tid;
        int t = c >> 4, d8 = (c & 15) << 3;
        uint4 x = *(const uint4*)&vp[(kb + t) * 128 + d8];
        const u16* xs = (const u16*)&x;
#pragma unroll
        for (int j = 0; j < 8; ++j) L[(d8 + j) * 66 + t] = xs[j];
    }
    __syncthreads();
#pragma unroll
    for (int i = 0; i < 4; ++i) {
        int c = i * 256 + tid;
        int d = c >> 3, t8 = (c & 7) << 3;
        uint4 x;
        u16* xs = (u16*)&x;
#pragma unroll
        for (int j = 0; j < 8; ++j) xs[j] = L[d * 66 + t8 + j];
        *(uint4*)&op[(size_t)d * 2048 + kb + t8] = x;
    }
}

// ---------------------------------------------------------------------------
// Flash attention (causal), shuffle softmax, Q-tile 128.
// Grid (16, 32): qt = 15 - blockIdx.x (heavy blocks dispatch first).
// 256 threads = 4 waves; wave w owns q-rows qt*128 + w*32 .. +31 (2 frags).
// q,k: [bh][s][128]; vt: [bh][d][s]; ctx: [b][s][h*128+d].
// ---------------------------------------------------------------------------
__global__ __launch_bounds__(256, 2) void attn_kernel(const u16* __restrict__ q,
                                                      const u16* __restrict__ k,
                                                      const u16* __restrict__ vt,
                                                      u16* __restrict__ ctx) {
    __shared__ __align__(16) u16 Ks[64 * 136];   // K [token][d]
    __shared__ __align__(16) u16 Vs[128 * 72];   // V^T [d][token]
    __shared__ __align__(16) u16 Ps[8][16 * 72]; // per (wave,frag) P 16x64

    const int tid = threadIdx.x;
    const int lane = tid & 63;
    const int wave = tid >> 6;
    const int quad = lane >> 4;
    const int m16 = lane & 15;
    const int qt = 15 - blockIdx.x;
    const int bh = blockIdx.y;
    const int b = bh >> 4, h = bh & 15;
    const int qbase = qt * 128;
    const u16* qp = q + (size_t)bh * 2048 * 128;
    const u16* kp = k + (size_t)bh * 2048 * 128;
    const u16* vp = vt + (size_t)bh * 128 * 2048;
    const float scale = 0.08838834764831845f;  // 1/sqrt(128)

    // Q fragments, 2 per wave (A-layout: row=m16, k=c*32+quad*8+j)
    bf16x8 qf[2][4];
#pragma unroll
    for (int f = 0; f < 2; ++f)
#pragma unroll
        for (int c = 0; c < 4; ++c)
            qf[f][c] = *(const bf16x8*)&qp[(qbase + wave * 32 + f * 16 + m16) *
                                               128 +
                                           c * 32 + quad * 8];

    const fx4 zero4 = {0.f, 0.f, 0.f, 0.f};
    fx4 o[2][8];
#pragma unroll
    for (int f = 0; f < 2; ++f)
#pragma unroll
        for (int i = 0; i < 8; ++i) o[f][i] = zero4;
    float mi[2][4], li[2][4];
#pragma unroll
    for (int f = 0; f < 2; ++f)
#pragma unroll
        for (int r = 0; r < 4; ++r) {
            mi[f][r] = -1e30f;
            li[f][r] = 0.f;
        }

    const int nkt = 2 * qt + 2;
    for (int kt = 0; kt < nkt; ++kt) {
        const int kb = kt * 64;
        // stage K [64][128] and V^T [128][64]
#pragma unroll
        for (int i = 0; i < 4; ++i) {
            int c = i * 256 + tid;
            {
                int t = c >> 4, d8 = (c & 15) << 3;
                *(uint4*)&Ks[t * 136 + d8] =
                    *(const uint4*)&kp[(kb + t) * 128 + d8];
            }
            {
                int d = c >> 3, t8 = (c & 7) << 3;
                *(uint4*)&Vs[d * 72 + t8] =
                    *(const uint4*)&vp[d * 2048 + kb + t8];
            }
        }
        __syncthreads();

#pragma unroll
        for (int f = 0; f < 2; ++f) {
            // QK^T: 16 rows x 64 cols
            fx4 sc[4];
#pragma unroll
            for (int nt = 0; nt < 4; ++nt) sc[nt] = zero4;
#pragma unroll
            for (int c = 0; c < 4; ++c)
#pragma unroll
                for (int nt = 0; nt < 4; ++nt) {
                    bf16x8 kf = *(const bf16x8*)&Ks[(nt * 16 + m16) * 136 +
                                                    c * 32 + quad * 8];
                    sc[nt] = MFMA16(qf[f][c], kf, sc[nt]);
                }

            // shuffle online softmax (row = quad*4+r, its 16 cols on lanes
            // quad*16..quad*16+15; xor 1/2/4/8 stays inside the group)
#pragma unroll
            for (int r = 0; r < 4; ++r) {
                int rg = qbase + wave * 32 + f * 16 + quad * 4 + r;
                float mx = mi[f][r];
#pragma unroll
                for (int nt = 0; nt < 4; ++nt) {
                    int cg = kb + nt * 16 + m16;
                    float s = sc[nt][r] * scale;
                    s = (cg <= rg) ? s : -1e30f;
                    sc[nt][r] = s;
                    mx = fmaxf(mx, s);
                }
                mx = fmaxf(mx, __shfl_xor(mx, 1));
                mx = fmaxf(mx, __shfl_xor(mx, 2));
                mx = fmaxf(mx, __shfl_xor(mx, 4));
                mx = fmaxf(mx, __shfl_xor(mx, 8));
                float alpha = __expf(mi[f][r] - mx);
                mi[f][r] = mx;
                float rsum = 0.f;
#pragma unroll
                for (int nt = 0; nt < 4; ++nt) {
                    float p = __expf(sc[nt][r] - mx);
                    Ps[wave * 2 + f][(quad * 4 + r) * 72 + nt * 16 + m16] =
                        f2bf(p);
                    rsum += p;
                }
                rsum += __shfl_xor(rsum, 1);
                rsum += __shfl_xor(rsum, 2);
                rsum += __shfl_xor(rsum, 4);
                rsum += __shfl_xor(rsum, 8);
                li[f][r] = li[f][r] * alpha + rsum;
#pragma unroll
                for (int dn = 0; dn < 8; ++dn) o[f][dn][r] *= alpha;
            }

            // O += P * V. Ps is wave-private: same-wave ds ordering suffices,
            // no barrier needed between write and read.
#pragma unroll
            for (int c2 = 0; c2 < 2; ++c2) {
                bf16x8 pf = *(const bf16x8*)&Ps[wave * 2 + f]
                                               [m16 * 72 + c2 * 32 + quad * 8];
#pragma unroll
                for (int dn = 0; dn < 8; ++dn) {
                    bf16x8 vf = *(const bf16x8*)&Vs[(dn * 16 + m16) * 72 +
                                                    c2 * 32 + quad * 8];
                    o[f][dn] = MFMA16(pf, vf, o[f][dn]);
                }
            }
        }
        __syncthreads();  // protect Ks/Vs before next tile's staging
    }

    // epilogue
#pragma unroll
    for (int f = 0; f < 2; ++f)
#pragma unroll
        for (int r = 0; r < 4; ++r) {
            int row = qbase + wave * 32 + f * 16 + quad * 4 + r;
            float inv = 1.0f / li[f][r];
#pragma unroll
            for (int dn = 0; dn < 8; ++dn) {
                int d = dn * 16 + m16;
                ctx[((size_t)(b * 2048 + row)) * 2048 + h * 128 + d] =
                    f2bf(o[f][dn][r] * inv);
            }
        }
}

// ---------------------------------------------------------------------------
extern "C" void kernel_launch(void* const* d_in, const int* in_sizes, int n_in,
                              void* d_out, int out_size, void* d_ws,
                              size_t ws_size, hipStream_t stream) {
    const float* x = (const float*)d_in[0];
    const float* wqkv_w = (const float*)d_in[1];
    const float* wqkv_b = (const float*)d_in[2];
    const float* out_w = (const float*)d_in[3];
    const float* out_b = (const float*)d_in[4];
    u16* ws = (u16*)d_ws;

    // ws: q | k | v | vt (bf16), 4 x 8388608 elements = 64 MiB. ctx reuses v.
    u16* qb = ws;
    u16* kb = ws + 8388608;
    u16* vb = ws + 16777216;
    u16* vtb = ws + 25165824;
    u16* ctx = vb;

    gemm_bt<1, 1><<<dim3(48, 32), 256, 0, stream>>>(x, wqkv_w, wqkv_b, qb,
                                                    4096, 6144, 2048);
    rope_kernel<<<16384, 256, 0, stream>>>(qb, kb);
    vtrans_kernel<<<dim3(32, 32), 256, 0, stream>>>(vb, vtb);
    attn_kernel<<<dim3(16, 32), 256, 0, stream>>>(qb, kb, vtb, ctx);
    gemm_bt<0, 0><<<dim3(16, 32), 256, 0, stream>>>(ctx, out_w, out_b, d_out,
                                                    4096, 2048, 2048);
}